// Round 6
// baseline (227.266 us; speedup 1.0000x reference)
//
#include <hip/hip_runtime.h>

#define IMG   4096
#define TW    64             // tile width
#define GC    68             // gray cols (TW + 4)
#define TH    32             // rows per tile
#define NT    8              // tiles per block (vertical)
#define BAND  (NT * TH)      // 256 output rows per block
#define RING  68             // gray ring rows (36 live + 32 incoming)
#define NBX   (IMG / TW)     // 64
#define NBY   (IMG / BAND)   // 16
#define W103  3.33333333333333f   // 10/3 (x3 scharr scale deferred to epilogue)

typedef float f32x4 __attribute__((ext_vector_type(4)));

__global__ __launch_bounds__(256, 4)
void harris_fused(const float* __restrict__ x,
                  float* __restrict__ out_edge,
                  float* __restrict__ out_eig)
{
    __shared__ float s_gray[RING * GC];      // 18,496 B ring of gray rows

    const int tid = threadIdx.x;
    const int bx = blockIdx.x, by = blockIdx.y;
    const int gx0 = bx * TW - 2;
    const int row0 = by * BAND;
    const bool bxi = (bx > 0) && (bx < NBX - 1);

    const float* __restrict__ x0 = x;
    const float* __restrict__ x1 = x + (size_t)IMG * IMG;
    const float* __restrict__ x2 = x + 2 * (size_t)IMG * IMG;

    float r0[10], r1[10], r2[10];            // staged raw channels for next tile

    // tile t contributes NEW gray rows: t==0 -> bg 0..35, else bg 32t+4 .. 32t+35
    // (bg = block-local gray row + 2; compute(t) reads bg in [32t, 32t+35])
    auto issue = [&](int t) {
        const int bg0 = (t == 0) ? 0 : 32 * t + 4;
        const int nel = ((t == 0) ? 36 : 32) * GC;
        const bool tin = bxi && !(t == 0 && by == 0) && !(t == NT - 1 && by == NBY - 1);
        const int base = (row0 + bg0 - 2) * IMG + gx0;
        if (tin) {
            #pragma unroll
            for (int k = 0; k < 10; ++k) {
                int idx = tid + k * 256;
                if (idx < nel) {
                    int r = (int)((unsigned)idx / (unsigned)GC);
                    int c = idx - r * GC;
                    int off = base + r * IMG + c;
                    r0[k] = x0[off]; r1[k] = x1[off]; r2[k] = x2[off];
                }
            }
        } else {
            #pragma unroll
            for (int k = 0; k < 10; ++k) {
                int idx = tid + k * 256;
                float a = 0.f, b = 0.f, c2 = 0.f;
                if (idx < nel) {
                    int r = (int)((unsigned)idx / (unsigned)GC);
                    int c = idx - r * GC;
                    int gy = row0 + bg0 - 2 + r;
                    int gx = gx0 + c;
                    if ((unsigned)gy < (unsigned)IMG && (unsigned)gx < (unsigned)IMG) {
                        int off = gy * IMG + gx;
                        a = x0[off]; b = x1[off]; c2 = x2[off];
                    }
                }
                r0[k] = a; r1[k] = b; r2[k] = c2;
            }
        }
    };

    auto commit = [&](int t) {
        const int bg0 = (t == 0) ? 0 : 32 * t + 4;
        const int nel = ((t == 0) ? 36 : 32) * GC;
        const int slot0 = bg0 % RING;
        #pragma unroll
        for (int k = 0; k < 10; ++k) {
            int idx = tid + k * 256;
            if (idx < nel) {
                int r = (int)((unsigned)idx / (unsigned)GC);
                int c = idx - r * GC;
                int s = slot0 + r; if (s >= RING) s -= RING;
                s_gray[s * GC + c] = 0.299f * r0[k] + 0.587f * r1[k] + 0.114f * r2[k];
            }
        }
    };

    const int tx = tid & 7;          // 0..7  -> col group
    const int v  = tid >> 3;         // 0..31 -> output row within tile
    const int c0 = tx * 8;           // gray-local col base (16B aligned)
    const int W0b = bx * TW;

    auto compute = [&](int t) {
        const int H0 = row0 + t * TH;
        const int bgv = t * TH + v;
        const int sv = bgv % RING;   // ring slot of this thread's l=0 gray row

        float ga[12], gb[12], gcx[12];
        float axx[10], ayy[10], axy[10];
        #pragma unroll
        for (int e = 0; e < 10; ++e) { axx[e] = 0.f; ayy[e] = 0.f; axy[e] = 0.f; }

        auto loadrow = [&](float* dst, int l) {
            int s = sv + l; if (s >= RING) s -= RING;
            const float4* p = reinterpret_cast<const float4*>(&s_gray[s * GC + c0]);
            float4 t0 = p[0], t1 = p[1], t2 = p[2];
            dst[0] = t0.x; dst[1] = t0.y; dst[2]  = t0.z; dst[3]  = t0.w;
            dst[4] = t1.x; dst[5] = t1.y; dst[6]  = t1.z; dst[7]  = t1.w;
            dst[8] = t2.x; dst[9] = t2.y; dst[10] = t2.z; dst[11] = t2.w;
        };

        auto contrib = [&](const float* top, const float* mid, const float* bot, int K) {
            float s[12], d[12];
            #pragma unroll
            for (int j = 0; j < 12; ++j) {
                s[j] = (top[j] + bot[j]) + W103 * mid[j];   // vertical smooth (/3)
                d[j] = bot[j] - top[j];                      // vertical diff
            }
            float ix[10], iy[10];
            #pragma unroll
            for (int e = 0; e < 10; ++e) {
                ix[e] = s[e + 2] - s[e];                               // Ix/3
                iy[e] = (d[e] + d[e + 2]) + W103 * d[e + 1];           // Iy/3
            }
            if (bx == 0       && tx == 0) { ix[0] = 0.f; iy[0] = 0.f; }
            if (bx == NBX - 1 && tx == 7) { ix[9] = 0.f; iy[9] = 0.f; }
            bool row_ok = true;
            if (K == 0 && t == 0      && by == 0       && v == 0)      row_ok = false;
            if (K == 2 && t == NT - 1 && by == NBY - 1 && v == TH - 1) row_ok = false;
            if (row_ok) {
                #pragma unroll
                for (int e = 0; e < 10; ++e) {
                    axx[e] += ix[e] * ix[e];
                    ayy[e] += iy[e] * iy[e];
                    axy[e] += ix[e] * iy[e];
                }
            }
            if (K == 1) {    // center row: edge magnitude = 1.5*(|ix'|+|iy'|)
                f32x4 m0, m1;
                m0.x = 1.5f * (fabsf(ix[1]) + fabsf(iy[1]));
                m0.y = 1.5f * (fabsf(ix[2]) + fabsf(iy[2]));
                m0.z = 1.5f * (fabsf(ix[3]) + fabsf(iy[3]));
                m0.w = 1.5f * (fabsf(ix[4]) + fabsf(iy[4]));
                m1.x = 1.5f * (fabsf(ix[5]) + fabsf(iy[5]));
                m1.y = 1.5f * (fabsf(ix[6]) + fabsf(iy[6]));
                m1.z = 1.5f * (fabsf(ix[7]) + fabsf(iy[7]));
                m1.w = 1.5f * (fabsf(ix[8]) + fabsf(iy[8]));
                const int off = (H0 + v) * IMG + W0b + c0;
                __builtin_nontemporal_store(m0, reinterpret_cast<f32x4*>(&out_edge[off]));
                __builtin_nontemporal_store(m1, reinterpret_cast<f32x4*>(&out_edge[off + 4]));
            }
        };

        loadrow(ga, 0); loadrow(gb, 1); loadrow(gcx, 2);
        contrib(ga, gb, gcx, 0);
        loadrow(ga, 3);
        contrib(gb, gcx, ga, 1);
        loadrow(gb, 4);
        contrib(gcx, ga, gb, 2);

        f32x4 e0, e1;
        #pragma unroll
        for (int q = 0; q < 8; ++q) {
            float sxx = axx[q] + axx[q + 1] + axx[q + 2];
            float syy = ayy[q] + ayy[q + 1] + ayy[q + 2];
            float sxy = axy[q] + axy[q + 1] + axy[q + 2];
            float diff = sxx - syy;
            float tr   = sxx + syy;
            float val  = 9.0f * (tr - sqrtf(diff * diff + 4.0f * sxy * sxy));
            if (q < 4) e0[q] = val; else e1[q - 4] = val;
        }
        const int off = (H0 + v) * IMG + W0b + c0;
        __builtin_nontemporal_store(e0, reinterpret_cast<f32x4*>(&out_eig[off]));
        __builtin_nontemporal_store(e1, reinterpret_cast<f32x4*>(&out_eig[off + 4]));
    };

    // ---- pipelined ring loop: issue(t+1) pinned above compute(t); commit after ----
    issue(0); commit(0); __syncthreads();

    #pragma unroll 1
    for (int t = 0; t < NT; ++t) {
        if (t + 1 < NT) issue(t + 1);
        __builtin_amdgcn_sched_barrier(0);   // loads stay issued above compute
        compute(t);
        __builtin_amdgcn_sched_barrier(0);   // commit's vmcnt waits stay below compute
        if (t + 1 < NT) { commit(t + 1); __syncthreads(); }
    }
}

extern "C" void kernel_launch(void* const* d_in, const int* in_sizes, int n_in,
                              void* d_out, int out_size, void* d_ws, size_t ws_size,
                              hipStream_t stream) {
    const float* x = (const float*)d_in[0];
    float* out      = (float*)d_out;
    float* out_edge = out;                       // output 0: (1,4096,4096)
    float* out_eig  = out + (size_t)IMG * IMG;   // output 1: (1,4096,4096)

    dim3 grid(NBX, NBY);
    harris_fused<<<grid, dim3(256), 0, stream>>>(x, out_edge, out_eig);
}

// Round 7
// 177.662 us; speedup vs baseline: 1.2792x; 1.2792x over previous
//
#include <hip/hip_runtime.h>

#define IMG   4096
#define TW    64             // output cols per wave tile
#define GC    68             // gray cols (TW + 4)
#define THR   8              // output rows per wave tile
#define GR    12             // gray rows per wave tile (THR + 4)
#define GN    (GR * GC)      // 816 floats = 3264 B per wave
#define NBX   (IMG / TW)     // 64
#define W103  3.33333333333333f   // 10/3 (x3 scharr scale deferred to epilogue)

typedef float f32x4 __attribute__((ext_vector_type(4)));

__global__ __launch_bounds__(256, 6)
void harris_fused(const float* __restrict__ x,
                  float* __restrict__ out_edge,
                  float* __restrict__ out_eig)
{
    __shared__ float s_gray[4][GN];          // 13,056 B; one private slice per wave

    const int tid  = threadIdx.x;
    const int wid  = tid >> 6;
    const int lane = tid & 63;
    const int bx   = blockIdx.x;
    const int row0 = blockIdx.y * 32 + wid * THR;   // top output row of this wave's tile
    const int gx0  = bx * TW - 2;
    const int gy0  = row0 - 2;

    const float* __restrict__ x0 = x;
    const float* __restrict__ x1 = x + (size_t)IMG * IMG;
    const float* __restrict__ x2 = x + 2 * (size_t)IMG * IMG;

    float* buf = s_gray[wid];

    // ---- wave-private staging: gray = 0.299R + 0.587G + 0.114B, zero-padded halo ----
    const bool tin = (bx > 0) && (bx < NBX - 1) && (row0 > 0) && (row0 < IMG - THR);
    if (tin) {
        #pragma unroll
        for (int k = 0; k < 13; ++k) {
            int idx = lane + k * 64;
            if (idx < GN) {                       // k==12: lanes < 48
                int r = (int)((unsigned)idx / (unsigned)GC);
                int c = idx - r * GC;
                int off = (gy0 + r) * IMG + (gx0 + c);
                buf[idx] = 0.299f * x0[off] + 0.587f * x1[off] + 0.114f * x2[off];
            }
        }
    } else {
        #pragma unroll
        for (int k = 0; k < 13; ++k) {
            int idx = lane + k * 64;
            if (idx < GN) {
                int r = (int)((unsigned)idx / (unsigned)GC);
                int c = idx - r * GC;
                int gy = gy0 + r, gx = gx0 + c;
                float g = 0.0f;
                if ((unsigned)gy < (unsigned)IMG && (unsigned)gx < (unsigned)IMG) {
                    int off = gy * IMG + gx;
                    g = 0.299f * x0[off] + 0.587f * x1[off] + 0.114f * x2[off];
                }
                buf[idx] = g;
            }
        }
    }
    __builtin_amdgcn_wave_barrier();   // compiler fence only; lgkmcnt waits cover LDS RAW

    // ---- compute: separable Scharr + 3x3 box + epilogues (same wave, no s_barrier) ----
    const int tx = lane & 7;           // 0..7  -> col group
    const int v  = lane >> 3;          // 0..7  -> output row within wave tile
    const int c0 = tx * 8;             // gray-local col base (16B aligned)
    const int W0b = bx * TW;

    float ga[12], gb[12], gcx[12];
    float axx[10], ayy[10], axy[10];
    #pragma unroll
    for (int e = 0; e < 10; ++e) { axx[e] = 0.f; ayy[e] = 0.f; axy[e] = 0.f; }

    auto loadrow = [&](float* dst, int l) {
        const float4* p = reinterpret_cast<const float4*>(&buf[(v + l) * GC + c0]);
        float4 t0 = p[0], t1 = p[1], t2 = p[2];
        dst[0] = t0.x; dst[1] = t0.y; dst[2]  = t0.z; dst[3]  = t0.w;
        dst[4] = t1.x; dst[5] = t1.y; dst[6]  = t1.z; dst[7]  = t1.w;
        dst[8] = t2.x; dst[9] = t2.y; dst[10] = t2.z; dst[11] = t2.w;
    };

    auto contrib = [&](const float* top, const float* mid, const float* bot, int K) {
        float s[12], d[12];
        #pragma unroll
        for (int j = 0; j < 12; ++j) {
            s[j] = (top[j] + bot[j]) + W103 * mid[j];   // vertical smooth (/3)
            d[j] = bot[j] - top[j];                      // vertical diff
        }
        float ix[10], iy[10];
        #pragma unroll
        for (int e = 0; e < 10; ++e) {
            ix[e] = s[e + 2] - s[e];                               // Ix/3
            iy[e] = (d[e] + d[e + 2]) + W103 * d[e + 1];           // Iy/3
        }
        if (bx == 0       && tx == 0) { ix[0] = 0.f; iy[0] = 0.f; }
        if (bx == NBX - 1 && tx == 7) { ix[9] = 0.f; iy[9] = 0.f; }
        bool row_ok = true;
        if (K == 0 && row0 == 0       && v == 0)       row_ok = false;  // edge row -1
        if (K == 2 && row0 == IMG-THR && v == THR - 1) row_ok = false;  // edge row 4096
        if (row_ok) {
            #pragma unroll
            for (int e = 0; e < 10; ++e) {
                axx[e] += ix[e] * ix[e];
                ayy[e] += iy[e] * iy[e];
                axy[e] += ix[e] * iy[e];
            }
        }
        if (K == 1) {      // center row: edge magnitude = 1.5*(|ix'|+|iy'|)
            f32x4 m0, m1;
            m0.x = 1.5f * (fabsf(ix[1]) + fabsf(iy[1]));
            m0.y = 1.5f * (fabsf(ix[2]) + fabsf(iy[2]));
            m0.z = 1.5f * (fabsf(ix[3]) + fabsf(iy[3]));
            m0.w = 1.5f * (fabsf(ix[4]) + fabsf(iy[4]));
            m1.x = 1.5f * (fabsf(ix[5]) + fabsf(iy[5]));
            m1.y = 1.5f * (fabsf(ix[6]) + fabsf(iy[6]));
            m1.z = 1.5f * (fabsf(ix[7]) + fabsf(iy[7]));
            m1.w = 1.5f * (fabsf(ix[8]) + fabsf(iy[8]));
            const int off = (row0 + v) * IMG + W0b + c0;
            __builtin_nontemporal_store(m0, reinterpret_cast<f32x4*>(&out_edge[off]));
            __builtin_nontemporal_store(m1, reinterpret_cast<f32x4*>(&out_edge[off + 4]));
        }
    };

    loadrow(ga, 0); loadrow(gb, 1); loadrow(gcx, 2);
    contrib(ga, gb, gcx, 0);
    loadrow(ga, 3);
    contrib(gb, gcx, ga, 1);
    loadrow(gb, 4);
    contrib(gcx, ga, gb, 2);

    f32x4 e0, e1;
    #pragma unroll
    for (int q = 0; q < 8; ++q) {
        float sxx = axx[q] + axx[q + 1] + axx[q + 2];
        float syy = ayy[q] + ayy[q + 1] + ayy[q + 2];
        float sxy = axy[q] + axy[q + 1] + axy[q + 2];
        float diff = sxx - syy;
        float tr   = sxx + syy;
        float val  = 9.0f * (tr - sqrtf(diff * diff + 4.0f * sxy * sxy));
        if (q < 4) e0[q] = val; else e1[q - 4] = val;
    }
    const int off = (row0 + v) * IMG + W0b + c0;
    __builtin_nontemporal_store(e0, reinterpret_cast<f32x4*>(&out_eig[off]));
    __builtin_nontemporal_store(e1, reinterpret_cast<f32x4*>(&out_eig[off + 4]));
}

extern "C" void kernel_launch(void* const* d_in, const int* in_sizes, int n_in,
                              void* d_out, int out_size, void* d_ws, size_t ws_size,
                              hipStream_t stream) {
    const float* x = (const float*)d_in[0];
    float* out      = (float*)d_out;
    float* out_edge = out;                       // output 0: (1,4096,4096)
    float* out_eig  = out + (size_t)IMG * IMG;   // output 1: (1,4096,4096)

    dim3 grid(NBX, IMG / 32);                    // 64 x 128 blocks; 4 wave-tiles per block
    harris_fused<<<grid, dim3(256), 0, stream>>>(x, out_edge, out_eig);
}

// Round 8
// 168.963 us; speedup vs baseline: 1.3451x; 1.0515x over previous
//
#include <hip/hip_runtime.h>

#define IMG   4096
#define TW    64             // output cols per block
#define TH    32             // output rows per block
#define GR    36             // gray rows (TH + 4)
#define GCA   72             // gray strip cols, 16B-aligned both ends (TW + 8)
#define NF4   18             // float4 per gray row
#define NPOS  (GR * NF4)     // 648 float4 positions per tile
#define NBX   (IMG / TW)     // 64
#define NBY   (IMG / TH)     // 128
#define W103  3.33333333333333f   // 10/3 (x3 scharr scale deferred to epilogue)

typedef float f32x4 __attribute__((ext_vector_type(4)));
typedef float f32x2 __attribute__((ext_vector_type(2)));

__global__ __launch_bounds__(256, 6)
void harris_fused(const float* __restrict__ x,
                  float* __restrict__ out_edge,
                  float* __restrict__ out_eig)
{
    __shared__ float s_gray[GR * GCA];       // 10,368 B

    const int tid = threadIdx.x;
    const int bx = blockIdx.x, by = blockIdx.y;
    const int row0 = by * TH;
    const int W0b  = bx * TW;
    const int gx0a = W0b - 4;                // 16B-aligned strip origin (cols gx0a..gx0a+71)
    const int gy0  = row0 - 2;
    const bool interior = (bx > 0) && (bx < NBX - 1) && (by > 0) && (by < NBY - 1);

    const float* __restrict__ x0 = x;
    const float* __restrict__ x1 = x + (size_t)IMG * IMG;
    const float* __restrict__ x2 = x + 2 * (size_t)IMG * IMG;

    // ---------------- Phase 1: vectorized gray staging (float4 loads, b128 LDS writes) ----
    if (interior) {
        const int base = gy0 * IMG + gx0a;
        #pragma unroll
        for (int k = 0; k < 3; ++k) {
            int p = tid + k * 256;
            if (p < NPOS) {                           // k<2 always true, k==2: tid<136
                int r = (int)((unsigned)p / (unsigned)NF4);
                int c4 = p - r * NF4;
                int off = base + r * IMG + 4 * c4;
                f32x4 a = *reinterpret_cast<const f32x4*>(&x0[off]);
                f32x4 b = *reinterpret_cast<const f32x4*>(&x1[off]);
                f32x4 c = *reinterpret_cast<const f32x4*>(&x2[off]);
                f32x4 g = 0.299f * a + 0.587f * b + 0.114f * c;
                *reinterpret_cast<f32x4*>(&s_gray[r * GCA + 4 * c4]) = g;
            }
        }
    } else {
        #pragma unroll
        for (int k = 0; k < 3; ++k) {
            int p = tid + k * 256;
            if (p < NPOS) {
                int r = (int)((unsigned)p / (unsigned)NF4);
                int c4 = p - r * NF4;
                int gy = gy0 + r;
                f32x4 g;
                #pragma unroll
                for (int comp = 0; comp < 4; ++comp) {
                    int gx = gx0a + 4 * c4 + comp;
                    float val = 0.0f;
                    if ((unsigned)gy < (unsigned)IMG && (unsigned)gx < (unsigned)IMG) {
                        int off = gy * IMG + gx;
                        val = 0.299f * x0[off] + 0.587f * x1[off] + 0.114f * x2[off];
                    }
                    g[comp] = val;
                }
                *reinterpret_cast<f32x4*>(&s_gray[r * GCA + 4 * c4]) = g;
            }
        }
    }
    __syncthreads();

    // ---------------- Phase 2: separable Scharr + 3x3 box + epilogues, 1x8 per thread -----
    const int tx = tid & 7;          // 0..7  -> col group
    const int v  = tid >> 3;         // 0..31 -> output row within tile
    const int c0 = tx * 8;           // output col base within tile

    float ga[12], gb[12], gcx[12];
    float axx[10], ayy[10], axy[10];
    #pragma unroll
    for (int e = 0; e < 10; ++e) { axx[e] = 0.f; ayy[e] = 0.f; axy[e] = 0.f; }

    // gray cols needed: global W0b+c0-2 .. W0b+c0+9  ->  LDS cols c0+2 .. c0+13
    auto loadrow = [&](float* dst, int l) {
        const float* p = &s_gray[(v + l) * GCA + c0 + 2];
        f32x2 t0 = *reinterpret_cast<const f32x2*>(p);        // +2,+3   (8B aligned)
        f32x4 t1 = *reinterpret_cast<const f32x4*>(p + 2);    // +4..+7  (16B aligned)
        f32x4 t2 = *reinterpret_cast<const f32x4*>(p + 6);    // +8..+11 (16B aligned)
        f32x2 t3 = *reinterpret_cast<const f32x2*>(p + 10);   // +12,+13 (8B aligned)
        dst[0] = t0.x; dst[1]  = t0.y;
        dst[2] = t1.x; dst[3]  = t1.y; dst[4]  = t1.z; dst[5]  = t1.w;
        dst[6] = t2.x; dst[7]  = t2.y; dst[8]  = t2.z; dst[9]  = t2.w;
        dst[10] = t3.x; dst[11] = t3.y;
    };

    auto contrib = [&](const float* top, const float* mid, const float* bot, int K) {
        float s[12], d[12];
        #pragma unroll
        for (int j = 0; j < 12; ++j) {
            s[j] = (top[j] + bot[j]) + W103 * mid[j];   // vertical smooth (/3)
            d[j] = bot[j] - top[j];                      // vertical diff
        }
        float ix[10], iy[10];
        #pragma unroll
        for (int e = 0; e < 10; ++e) {
            ix[e] = s[e + 2] - s[e];                               // Ix/3
            iy[e] = (d[e] + d[e + 2]) + W103 * d[e + 1];           // Iy/3
        }
        if (bx == 0       && tx == 0) { ix[0] = 0.f; iy[0] = 0.f; }
        if (bx == NBX - 1 && tx == 7) { ix[9] = 0.f; iy[9] = 0.f; }
        bool row_ok = true;
        if (K == 0 && by == 0       && v == 0)      row_ok = false;  // edge row -1
        if (K == 2 && by == NBY - 1 && v == TH - 1) row_ok = false;  // edge row 4096
        if (row_ok) {
            #pragma unroll
            for (int e = 0; e < 10; ++e) {
                axx[e] += ix[e] * ix[e];
                ayy[e] += iy[e] * iy[e];
                axy[e] += ix[e] * iy[e];
            }
        }
        if (K == 1) {      // center row: edge magnitude = 1.5*(|ix'|+|iy'|)
            f32x4 m0, m1;
            m0.x = 1.5f * (fabsf(ix[1]) + fabsf(iy[1]));
            m0.y = 1.5f * (fabsf(ix[2]) + fabsf(iy[2]));
            m0.z = 1.5f * (fabsf(ix[3]) + fabsf(iy[3]));
            m0.w = 1.5f * (fabsf(ix[4]) + fabsf(iy[4]));
            m1.x = 1.5f * (fabsf(ix[5]) + fabsf(iy[5]));
            m1.y = 1.5f * (fabsf(ix[6]) + fabsf(iy[6]));
            m1.z = 1.5f * (fabsf(ix[7]) + fabsf(iy[7]));
            m1.w = 1.5f * (fabsf(ix[8]) + fabsf(iy[8]));
            const int off = (row0 + v) * IMG + W0b + c0;
            __builtin_nontemporal_store(m0, reinterpret_cast<f32x4*>(&out_edge[off]));
            __builtin_nontemporal_store(m1, reinterpret_cast<f32x4*>(&out_edge[off + 4]));
        }
    };

    loadrow(ga, 0); loadrow(gb, 1); loadrow(gcx, 2);
    contrib(ga, gb, gcx, 0);
    loadrow(ga, 3);
    contrib(gb, gcx, ga, 1);
    loadrow(gb, 4);
    contrib(gcx, ga, gb, 2);

    f32x4 e0, e1;
    #pragma unroll
    for (int q = 0; q < 8; ++q) {
        float sxx = axx[q] + axx[q + 1] + axx[q + 2];
        float syy = ayy[q] + ayy[q + 1] + ayy[q + 2];
        float sxy = axy[q] + axy[q + 1] + axy[q + 2];
        float diff = sxx - syy;
        float tr   = sxx + syy;
        float val  = 9.0f * (tr - sqrtf(diff * diff + 4.0f * sxy * sxy));
        if (q < 4) e0[q] = val; else e1[q - 4] = val;
    }
    const int off = (row0 + v) * IMG + W0b + c0;
    __builtin_nontemporal_store(e0, reinterpret_cast<f32x4*>(&out_eig[off]));
    __builtin_nontemporal_store(e1, reinterpret_cast<f32x4*>(&out_eig[off + 4]));
}

extern "C" void kernel_launch(void* const* d_in, const int* in_sizes, int n_in,
                              void* d_out, int out_size, void* d_ws, size_t ws_size,
                              hipStream_t stream) {
    const float* x = (const float*)d_in[0];
    float* out      = (float*)d_out;
    float* out_edge = out;                       // output 0: (1,4096,4096)
    float* out_eig  = out + (size_t)IMG * IMG;   // output 1: (1,4096,4096)

    dim3 grid(NBX, NBY);
    harris_fused<<<grid, dim3(256), 0, stream>>>(x, out_edge, out_eig);
}

// Round 9
// 92.766 us; speedup vs baseline: 2.4499x; 1.8214x over previous
//
#include <hip/hip_runtime.h>

#define IMG   4096
#define TW    64             // output cols per block
#define TH    32             // output rows per block
#define GR    36             // gray rows (TH + 4)
#define GST   76             // LDS row stride (76 mod 32 = 12 -> 2-way max on reads)
#define NF4   18             // float4 per gray row (72 data cols: W0b-4 .. W0b+67)
#define NPOS  (GR * NF4)     // 648 float4 positions per tile
#define NBX   (IMG / TW)     // 64
#define NBY   (IMG / TH)     // 128
#define W103  3.33333333333333f   // 10/3 (x3 scharr scale deferred to epilogue)

typedef float f32x4 __attribute__((ext_vector_type(4)));
typedef float f32x2 __attribute__((ext_vector_type(2)));

__global__ __launch_bounds__(256, 4)
void harris_fused(const float* __restrict__ x,
                  float* __restrict__ out_edge,
                  float* __restrict__ out_eig)
{
    __shared__ float s_gray[GR * GST];       // 10,944 B

    const int tid = threadIdx.x;
    const int bx = blockIdx.x, by = blockIdx.y;
    const int row0 = by * TH;
    const int W0b  = bx * TW;
    const int gx0a = W0b - 4;                // 16B-aligned strip origin
    const int gy0  = row0 - 2;
    const bool interior = (bx > 0) && (bx < NBX - 1) && (by > 0) && (by < NBY - 1);

    const float* __restrict__ x0 = x;
    const float* __restrict__ x1 = x + (size_t)IMG * IMG;
    const float* __restrict__ x2 = x + 2 * (size_t)IMG * IMG;

    // ---------------- Phase 1: gray staging via aligned float4 loads ----------------------
    if (interior) {
        const int base = gy0 * IMG + gx0a;
        #pragma unroll
        for (int k = 0; k < 3; ++k) {
            int p = tid + k * 256;
            if (p < NPOS) {                           // k<2 always true, k==2: tid<136
                int r = (int)((unsigned)p / (unsigned)NF4);
                int c4 = p - r * NF4;
                int off = base + r * IMG + 4 * c4;
                f32x4 a = *reinterpret_cast<const f32x4*>(&x0[off]);
                f32x4 b = *reinterpret_cast<const f32x4*>(&x1[off]);
                f32x4 c = *reinterpret_cast<const f32x4*>(&x2[off]);
                f32x4 g = 0.299f * a + 0.587f * b + 0.114f * c;
                *reinterpret_cast<f32x4*>(&s_gray[r * GST + 4 * c4]) = g;
            }
        }
    } else {
        #pragma unroll
        for (int k = 0; k < 3; ++k) {
            int p = tid + k * 256;
            if (p < NPOS) {
                int r = (int)((unsigned)p / (unsigned)NF4);
                int c4 = p - r * NF4;
                int gy = gy0 + r;
                f32x4 g;
                #pragma unroll
                for (int comp = 0; comp < 4; ++comp) {
                    int gx = gx0a + 4 * c4 + comp;
                    float val = 0.0f;
                    if ((unsigned)gy < (unsigned)IMG && (unsigned)gx < (unsigned)IMG) {
                        int off = gy * IMG + gx;
                        val = 0.299f * x0[off] + 0.587f * x1[off] + 0.114f * x2[off];
                    }
                    g[comp] = val;
                }
                *reinterpret_cast<f32x4*>(&s_gray[r * GST + 4 * c4]) = g;
            }
        }
    }
    __syncthreads();

    // ---------------- Phase 2: separable Scharr + 3x3 box + epilogues, 1x8 per thread -----
    const int tx = tid & 7;          // 0..7  -> col group
    const int v  = tid >> 3;         // 0..31 -> output row within tile
    const int c0 = tx * 8;           // output col base within tile

    float ga[12], gb[12], gcx[12];
    float axx[10], ayy[10], axy[10];
    #pragma unroll
    for (int e = 0; e < 10; ++e) { axx[e] = 0.f; ayy[e] = 0.f; axy[e] = 0.f; }

    // gray cols needed: global W0b+c0-2 .. W0b+c0+9  ->  LDS cols c0+2 .. c0+13
    auto loadrow = [&](float* dst, int l) {
        const float* p = &s_gray[(v + l) * GST + c0 + 2];
        f32x2 t0 = *reinterpret_cast<const f32x2*>(p);        // +2,+3   (8B aligned)
        f32x4 t1 = *reinterpret_cast<const f32x4*>(p + 2);    // +4..+7  (16B aligned)
        f32x4 t2 = *reinterpret_cast<const f32x4*>(p + 6);    // +8..+11 (16B aligned)
        f32x2 t3 = *reinterpret_cast<const f32x2*>(p + 10);   // +12,+13 (8B aligned)
        dst[0] = t0.x; dst[1]  = t0.y;
        dst[2] = t1.x; dst[3]  = t1.y; dst[4]  = t1.z; dst[5]  = t1.w;
        dst[6] = t2.x; dst[7]  = t2.y; dst[8]  = t2.z; dst[9]  = t2.w;
        dst[10] = t3.x; dst[11] = t3.y;
    };

    auto contrib = [&](const float* top, const float* mid, const float* bot, int K) {
        float s[12], d[12];
        #pragma unroll
        for (int j = 0; j < 12; ++j) {
            s[j] = (top[j] + bot[j]) + W103 * mid[j];   // vertical smooth (/3)
            d[j] = bot[j] - top[j];                      // vertical diff
        }
        float ix[10], iy[10];
        #pragma unroll
        for (int e = 0; e < 10; ++e) {
            ix[e] = s[e + 2] - s[e];                               // Ix/3
            iy[e] = (d[e] + d[e + 2]) + W103 * d[e + 1];           // Iy/3
        }
        if (bx == 0       && tx == 0) { ix[0] = 0.f; iy[0] = 0.f; }
        if (bx == NBX - 1 && tx == 7) { ix[9] = 0.f; iy[9] = 0.f; }
        bool row_ok = true;
        if (K == 0 && by == 0       && v == 0)      row_ok = false;  // edge row -1
        if (K == 2 && by == NBY - 1 && v == TH - 1) row_ok = false;  // edge row 4096
        if (row_ok) {
            #pragma unroll
            for (int e = 0; e < 10; ++e) {
                axx[e] += ix[e] * ix[e];
                ayy[e] += iy[e] * iy[e];
                axy[e] += ix[e] * iy[e];
            }
        }
        if (K == 1) {      // center row: edge magnitude = 1.5*(|ix'|+|iy'|)
            f32x4 m0, m1;
            m0.x = 1.5f * (fabsf(ix[1]) + fabsf(iy[1]));
            m0.y = 1.5f * (fabsf(ix[2]) + fabsf(iy[2]));
            m0.z = 1.5f * (fabsf(ix[3]) + fabsf(iy[3]));
            m0.w = 1.5f * (fabsf(ix[4]) + fabsf(iy[4]));
            m1.x = 1.5f * (fabsf(ix[5]) + fabsf(iy[5]));
            m1.y = 1.5f * (fabsf(ix[6]) + fabsf(iy[6]));
            m1.z = 1.5f * (fabsf(ix[7]) + fabsf(iy[7]));
            m1.w = 1.5f * (fabsf(ix[8]) + fabsf(iy[8]));
            const int off = (row0 + v) * IMG + W0b + c0;
            __builtin_nontemporal_store(m0, reinterpret_cast<f32x4*>(&out_edge[off]));
            __builtin_nontemporal_store(m1, reinterpret_cast<f32x4*>(&out_edge[off + 4]));
        }
    };

    loadrow(ga, 0); loadrow(gb, 1); loadrow(gcx, 2);
    contrib(ga, gb, gcx, 0);
    loadrow(ga, 3);
    contrib(gb, gcx, ga, 1);
    loadrow(gb, 4);
    contrib(gcx, ga, gb, 2);

    f32x4 e0, e1;
    #pragma unroll
    for (int q = 0; q < 8; ++q) {
        float sxx = axx[q] + axx[q + 1] + axx[q + 2];
        float syy = ayy[q] + ayy[q + 1] + ayy[q + 2];
        float sxy = axy[q] + axy[q + 1] + axy[q + 2];
        float diff = sxx - syy;
        float tr   = sxx + syy;
        float val  = 9.0f * (tr - sqrtf(diff * diff + 4.0f * sxy * sxy));
        if (q < 4) e0[q] = val; else e1[q - 4] = val;
    }
    const int off = (row0 + v) * IMG + W0b + c0;
    __builtin_nontemporal_store(e0, reinterpret_cast<f32x4*>(&out_eig[off]));
    __builtin_nontemporal_store(e1, reinterpret_cast<f32x4*>(&out_eig[off + 4]));
}

extern "C" void kernel_launch(void* const* d_in, const int* in_sizes, int n_in,
                              void* d_out, int out_size, void* d_ws, size_t ws_size,
                              hipStream_t stream) {
    const float* x = (const float*)d_in[0];
    float* out      = (float*)d_out;
    float* out_edge = out;                       // output 0: (1,4096,4096)
    float* out_eig  = out + (size_t)IMG * IMG;   // output 1: (1,4096,4096)

    dim3 grid(NBX, NBY);
    harris_fused<<<grid, dim3(256), 0, stream>>>(x, out_edge, out_eig);
}

// Round 10
// 81.242 us; speedup vs baseline: 2.7974x; 1.1418x over previous
//
#include <hip/hip_runtime.h>

#define IMG  4096
#define H    64              // output rows per wave strip
#define UC   60              // useful output cols per wave (lanes 2..61)
#define NCG  69              // col groups: ceil(4096/60)
#define W103 3.33333333333333f   // 10/3 (x3 scharr scale deferred to epilogue)

__global__ __launch_bounds__(256)
void harris_stream(const float* __restrict__ x,
                   float* __restrict__ out_edge,
                   float* __restrict__ out_eig)
{
    const int lane  = threadIdx.x;                    // 0..63
    const int strip = blockIdx.y * 4 + threadIdx.y;   // 0..63 (4 adjacent strips/block)
    const int r0    = strip * H;
    const int c_g   = blockIdx.x * UC + lane - 2;     // this lane's global column
    const bool cvalid = (unsigned)c_g < (unsigned)IMG;
    const int  c_cl   = min(max(c_g, 0), IMG - 1);
    const bool cstore = cvalid && (lane >= 2) && (lane <= 61);

    const float* __restrict__ x0 = x;
    const float* __restrict__ x1 = x + (size_t)IMG * IMG;
    const float* __restrict__ x2 = x + 2 * (size_t)IMG * IMG;

    const int lo = c_cl;                     // clamped index range for safe loads
    const int hi = (IMG - 1) * IMG + c_cl;
    const int lm = (lane + 63) & 63;
    const int lp = (lane + 1) & 63;

    // branchless gray loader: clamped-safe address, zero outside image
    auto gray = [&](int gr) -> float {
        int idx = gr * IMG + c_cl;                       // gr*4096 -> shift
        int idc = idx < lo ? lo : (idx > hi ? hi : idx); // med3
        float g = 0.299f * x0[idc] + 0.587f * x1[idc] + 0.114f * x2[idc];
        bool ok = (idx == idc) && cvalid;
        return ok ? g : 0.0f;
    };

    float ga, gb, gc;                        // gray ring: rows e-1, e, e+1
    gb = gray(r0 - 2);
    gc = gray(r0 - 1);
    float hxx1 = 0.f, hyy1 = 0.f, hxy1 = 0.f;   // h sums at edge row e-1
    float hxx2 = 0.f, hyy2 = 0.f, hxy2 = 0.f;   // h sums at edge row e-2

    #pragma unroll 3
    for (int t = 0; t < H + 2; ++t) {        // e = edge row being produced
        const int e = r0 - 1 + t;
        ga = gb; gb = gc; gc = gray(e + 1);

        float s = (ga + gc) + W103 * gb;     // vertical smooth (/3)
        float d = gc - ga;                   // vertical diff
        float sm = __shfl(s, lm, 64);
        float sp = __shfl(s, lp, 64);
        float dm = __shfl(d, lm, 64);
        float dp = __shfl(d, lp, 64);
        float ix = sp - sm;                              // Ix/3 at (e, c)
        float iy = (dm + dp) + W103 * d;                 // Iy/3 at (e, c)
        const bool ev = ((unsigned)e < (unsigned)IMG) && cvalid;
        ix = ev ? ix : 0.0f;
        iy = ev ? iy : 0.0f;

        if (e >= r0 && e < r0 + H) {         // edge magnitude = 1.5*(|ix'|+|iy'|)
            if (cstore)
                __builtin_nontemporal_store(1.5f * (fabsf(ix) + fabsf(iy)),
                                            &out_edge[e * IMG + c_g]);
        }

        float ixm = __shfl(ix, lm, 64);
        float ixp = __shfl(ix, lp, 64);
        float iym = __shfl(iy, lm, 64);
        float iyp = __shfl(iy, lp, 64);
        float hxx = ixm * ixm + ix * ix + ixp * ixp;     // horizontal 3-sum of products
        float hyy = iym * iym + iy * iy + iyp * iyp;
        float hxy = ixm * iym + ix * iy + ixp * iyp;

        if (t >= 2) {                        // output row o = e-1 (needs rows e-2,e-1,e)
            const int o = e - 1;
            float sxx = hxx2 + hxx1 + hxx;
            float syy = hyy2 + hyy1 + hyy;
            float sxy = hxy2 + hxy1 + hxy;
            float diff = sxx - syy;
            float tr   = sxx + syy;
            float t2   = 2.0f * sxy;
            float val  = 9.0f * (tr - sqrtf(diff * diff + t2 * t2));
            if (cstore)
                __builtin_nontemporal_store(val, &out_eig[o * IMG + c_g]);
        }
        hxx2 = hxx1; hxx1 = hxx;
        hyy2 = hyy1; hyy1 = hyy;
        hxy2 = hxy1; hxy1 = hxy;
    }
}

extern "C" void kernel_launch(void* const* d_in, const int* in_sizes, int n_in,
                              void* d_out, int out_size, void* d_ws, size_t ws_size,
                              hipStream_t stream) {
    const float* x = (const float*)d_in[0];
    float* out      = (float*)d_out;
    float* out_edge = out;                       // output 0: (1,4096,4096)
    float* out_eig  = out + (size_t)IMG * IMG;   // output 1: (1,4096,4096)

    dim3 grid(NCG, 16);                          // 69 col groups x 16 blocks x 4 strips
    dim3 block(64, 4);
    harris_stream<<<grid, block, 0, stream>>>(x, out_edge, out_eig);
}

// Round 11
// 74.277 us; speedup vs baseline: 3.0597x; 1.0938x over previous
//
#include <hip/hip_runtime.h>

#define IMG  4096
#define H    32              // output rows per wave strip
#define UC   248             // useful output cols per wave (lanes 1..62, 4 each)
#define NCG  17              // col groups: ceil(4096/248)
#define NSTR (IMG / H)       // 128 strips
#define W103 3.33333333333333f   // 10/3 (x3 scharr scale deferred to epilogue)

typedef float f32x4 __attribute__((ext_vector_type(4)));

__global__ __launch_bounds__(256)
void harris_stream4(const float* __restrict__ x,
                    float* __restrict__ out_edge,
                    float* __restrict__ out_eig)
{
    const int lane  = threadIdx.x;                    // 0..63
    const int strip = blockIdx.y * 4 + threadIdx.y;   // 4 adjacent strips per block
    const int r0    = strip * H;
    const int cb    = blockIdx.x * UC - 4 + 4 * lane; // this lane's col base (mult of 4)
    const bool cval = (unsigned)cb < (unsigned)IMG;   // whole float4 valid or invalid
    const int  cbl  = cval ? cb : 0;
    const bool sval = cval && (lane >= 1) && (lane <= 62);
    const int  lm = (lane + 63) & 63, lp = (lane + 1) & 63;

    const float* __restrict__ x0 = x;
    const float* __restrict__ x1 = x + (size_t)IMG * IMG;
    const float* __restrict__ x2 = x + 2 * (size_t)IMG * IMG;

    const f32x4 VZERO = {0.f, 0.f, 0.f, 0.f};

    auto raddr = [&](int r) -> int {                  // clamped, always-safe address
        int rc = min(max(r, 0), IMG - 1);
        return rc * IMG + cbl;
    };
    auto mkgray = [&](f32x4 a, f32x4 b, f32x4 c, int r) -> f32x4 {
        f32x4 gv = 0.299f * a + 0.587f * b + 0.114f * c;
        bool ok = ((unsigned)r < (unsigned)IMG) && cval;
        return ok ? gv : VZERO;
    };

    // ---- init: gray ring rows r0-2, r0-1; prefetch raw row r0 ----
    f32x4 ga, gb, gc;
    {
        int o = raddr(r0 - 2);
        gb = mkgray(*(const f32x4*)(x0 + o), *(const f32x4*)(x1 + o),
                    *(const f32x4*)(x2 + o), r0 - 2);
        o = raddr(r0 - 1);
        gc = mkgray(*(const f32x4*)(x0 + o), *(const f32x4*)(x1 + o),
                    *(const f32x4*)(x2 + o), r0 - 1);
    }
    int po = raddr(r0);
    f32x4 pa = *(const f32x4*)(x0 + po);
    f32x4 pb = *(const f32x4*)(x1 + po);
    f32x4 pc = *(const f32x4*)(x2 + po);

    f32x4 hxx1 = VZERO, hyy1 = VZERO, hxy1 = VZERO;   // h sums at edge row e-1
    f32x4 hxx2 = VZERO, hyy2 = VZERO, hxy2 = VZERO;   // h sums at edge row e-2

    #pragma unroll 2
    for (int t = 0; t <= H + 1; ++t) {                // e = edge row being produced
        const int e = r0 - 1 + t;

        // consume prefetched raw row (e+1), immediately issue prefetch of row e+2
        f32x4 ra = pa, rb = pb, rc = pc;
        int no = raddr(e + 2);
        pa = *(const f32x4*)(x0 + no);
        pb = *(const f32x4*)(x1 + no);
        pc = *(const f32x4*)(x2 + no);

        ga = gb; gb = gc;
        gc = mkgray(ra, rb, rc, e + 1);

        f32x4 s = (ga + gc) + W103 * gb;              // vertical smooth (/3)
        f32x4 d = gc - ga;                            // vertical diff
        float smL = __shfl(s.w, lm, 64);
        float spR = __shfl(s.x, lp, 64);
        float dmL = __shfl(d.w, lm, 64);
        float dpR = __shfl(d.x, lp, 64);
        float sx[6] = {smL, s.x, s.y, s.z, s.w, spR};
        float dx[6] = {dmL, d.x, d.y, d.z, d.w, dpR};
        f32x4 ix, iy;
        #pragma unroll
        for (int k = 0; k < 4; ++k) {
            ix[k] = sx[k + 2] - sx[k];                         // Ix/3
            iy[k] = (dx[k] + dx[k + 2]) + W103 * dx[k + 1];    // Iy/3
        }
        const bool ev = ((unsigned)e < (unsigned)IMG) && cval;
        if (!ev) { ix = VZERO; iy = VZERO; }          // conv zero-padding outside image

        if (t >= 1 && t <= H && sval) {               // edge mag = 1.5*(|ix'|+|iy'|)
            f32x4 m;
            #pragma unroll
            for (int k = 0; k < 4; ++k)
                m[k] = 1.5f * (fabsf(ix[k]) + fabsf(iy[k]));
            __builtin_nontemporal_store(m, (f32x4*)(&out_edge[e * IMG + cb]));
        }

        float ixmL = __shfl(ix.w, lm, 64);
        float ixpR = __shfl(ix.x, lp, 64);
        float iymL = __shfl(iy.w, lm, 64);
        float iypR = __shfl(iy.x, lp, 64);
        float ixa[6] = {ixmL, ix.x, ix.y, ix.z, ix.w, ixpR};
        float iya[6] = {iymL, iy.x, iy.y, iy.z, iy.w, iypR};
        float qxx[6], qyy[6], qxy[6];
        #pragma unroll
        for (int j = 0; j < 6; ++j) {
            qxx[j] = ixa[j] * ixa[j];
            qyy[j] = iya[j] * iya[j];
            qxy[j] = ixa[j] * iya[j];
        }
        f32x4 hxx, hyy, hxy;
        #pragma unroll
        for (int k = 0; k < 4; ++k) {
            hxx[k] = qxx[k] + qxx[k + 1] + qxx[k + 2];
            hyy[k] = qyy[k] + qyy[k + 1] + qyy[k + 2];
            hxy[k] = qxy[k] + qxy[k + 1] + qxy[k + 2];
        }

        if (t >= 2 && sval) {                         // output row o = e-1
            const int o = e - 1;
            f32x4 vv;
            #pragma unroll
            for (int k = 0; k < 4; ++k) {
                float sxx = hxx2[k] + hxx1[k] + hxx[k];
                float syy = hyy2[k] + hyy1[k] + hyy[k];
                float sxy = hxy2[k] + hxy1[k] + hxy[k];
                float diff = sxx - syy;
                float tr   = sxx + syy;
                float t2   = 2.0f * sxy;
                vv[k] = 9.0f * (tr - sqrtf(diff * diff + t2 * t2));
            }
            __builtin_nontemporal_store(vv, (f32x4*)(&out_eig[o * IMG + cb]));
        }
        hxx2 = hxx1; hxx1 = hxx;
        hyy2 = hyy1; hyy1 = hyy;
        hxy2 = hxy1; hxy1 = hxy;
    }
}

extern "C" void kernel_launch(void* const* d_in, const int* in_sizes, int n_in,
                              void* d_out, int out_size, void* d_ws, size_t ws_size,
                              hipStream_t stream) {
    const float* x = (const float*)d_in[0];
    float* out      = (float*)d_out;
    float* out_edge = out;                       // output 0: (1,4096,4096)
    float* out_eig  = out + (size_t)IMG * IMG;   // output 1: (1,4096,4096)

    dim3 grid(NCG, NSTR / 4);                    // 17 col groups x 32 blocks x 4 strips
    dim3 block(64, 4);
    harris_stream4<<<grid, block, 0, stream>>>(x, out_edge, out_eig);
}